// Round 14
// baseline (46.062 us; speedup 1.0000x reference)
//
#include <hip/hip_runtime.h>
#include <float.h>

#define BB 32
#define CC 128
#define NP 4   // planes per block (sequential 64KB stream)

// Stream-everything kernel: block = NP consecutive (b,c) planes; the whole
// 64MB input is read once, sequentially, double-buffered through LDS.
// Pipeline per plane q: compute(q from buf[q&1]) || loads(q+2 in flight);
// then store regs(q+1)->buf[~], prefetch(q+2), one barrier.
// 4 waves/block; wave w computes landmarks {2w, 2w+1} of its plane from LDS.
// Grid = 32*128/NP = 1024 blocks.
__global__ __launch_bounds__(256) void roipool_kernel(
    const float* __restrict__ x,   // [B,C,64,64]
    const float* __restrict__ lm,  // [B,16]
    float* __restrict__ out)       // [B,C,32,16]
{
    int p0 = blockIdx.x * NP;      // first plane (b*128+c); NP|128 -> b const
    int b  = p0 >> 7;
    int c0 = p0 & 127;

    int tid  = threadIdx.x;
    int wave = tid >> 6;
    int lane = tid & 63;

    __shared__ float s[2][64][64];   // 32 KB double-buffered plane
    __shared__ float tb[4][8][65];   // per-wave bin-max (padded: i -> bank shift)

    // per-wave landmark params, hoisted across planes (b constant)
    int fxA[2], roiA[2]; bool visA[2];
    #pragma unroll
    for (int k = 0; k < 2; ++k) {
        int lmi = 2 * wave + k;
        float x0 = lm[b * 16 + 2 * lmi];
        float y0 = lm[b * 16 + 2 * lmi + 1];
        visA[k] = (x0 > 0.0f) || (y0 > 0.0f);
        // torchvision column-swap semantics:
        // rois=(b,x1,x2,y1,y2) consumed as (b,start_w,start_h,end_w,end_h)
        int fx = (int)floorf(x0 * 0.25f);
        int fy = (int)floorf(y0 * 0.25f);
        fxA[k]  = fx;
        roiA[k] = max(fy - fx + 1, 1);   // roi_w == roi_h
    }

    int i = lane >> 3;   // cell row
    int j = lane & 7;    // cell col

    // ---- prologue: plane 0 -> buf0; prefetch plane 1 ----
    const float4* pl = (const float4*)(x + ((size_t)p0 << 12));
    float4 r0 = pl[tid], r1 = pl[tid + 256], r2 = pl[tid + 512], r3 = pl[tid + 768];
    {
        float4* d = (float4*)&s[0][0][0];
        d[tid] = r0; d[tid + 256] = r1; d[tid + 512] = r2; d[tid + 768] = r3;
    }
    pl = (const float4*)(x + ((size_t)(p0 + 1) << 12));
    r0 = pl[tid]; r1 = pl[tid + 256]; r2 = pl[tid + 512]; r3 = pl[tid + 768];
    __syncthreads();

    #pragma unroll
    for (int q = 0; q < NP; ++q) {
        const int buf = q & 1;
        int c = c0 + q;

        // ---- compute plane q from s[buf]; wave-local, no barriers ----
        #pragma unroll
        for (int k = 0; k < 2; ++k) {
            int lmi = 2 * wave + k;
            int fx = fxA[k], roi = roiA[k];
            int orow = 8 * (lmi >> 1) + i;
            int ocol = 8 * (lmi & 1) + j;
            size_t oidx = (((size_t)(b * CC + c)) * 32 + orow) * 16 + ocol;

            if (!visA[k]) { out[oidx] = 0.0f; continue; }   // wave-uniform

            if (roi == 1) {   // all 64 cells = pixel (fx, fx-7); LDS broadcast
                int hs = min(max(fx, 0), 64),     he = min(max(fx + 1, 0), 64);
                int ws = min(max(fx - 7, 0), 64), we = min(max(fx - 6, 0), 64);
                bool empty = (he <= hs) || (we <= ws);
                out[oidx] = empty ? 0.0f : s[buf][hs][ws];
                continue;
            }

            // stage 1: per-column max per row-bin (lane = col); exact int bounds
            #pragma unroll
            for (int t = 0; t < 8; ++t) {
                int hs = min(max(((t * roi) >> 3) + fx, 0), 64);
                int he = min(max((((t + 1) * roi + 7) >> 3) + fx, 0), 64);
                float acc = -FLT_MAX;
                for (int h = hs; h < he; h += 4) {
                    int hm = he - 1;    // clamped dup rows harmless under max
                    float a0 = s[buf][h][lane];
                    float a1 = s[buf][min(h + 1, hm)][lane];
                    float a2 = s[buf][min(h + 2, hm)][lane];
                    float a3 = s[buf][min(h + 3, hm)][lane];
                    acc = fmaxf(acc, fmaxf(fmaxf(a0, a1), fmaxf(a2, a3)));
                }
                tb[wave][t][lane] = acc;
            }

            // stage 2: pool bin-max columns (same wave wrote tb -> no barrier)
            int hs = min(max(((i * roi) >> 3) + fx, 0), 64);
            int he = min(max((((i + 1) * roi + 7) >> 3) + fx, 0), 64);
            int ws = min(max(((j * roi) >> 3) + fx - 7, 0), 64);
            int we = min(max((((j + 1) * roi + 7) >> 3) + fx - 7, 0), 64);
            bool empty = (he <= hs) || (we <= ws);
            float m = -FLT_MAX;
            if (!empty) {
                for (int w = ws; w < we; ++w)
                    m = fmaxf(m, tb[wave][i][w]);
            }
            out[oidx] = empty ? 0.0f : m;
        }

        // ---- store plane q+1 (loads landed during compute), prefetch q+2 ----
        if (q + 1 < NP) {
            // buf^1 was last READ in compute(q-1), finished at previous barrier
            float4* d = (float4*)&s[buf ^ 1][0][0];
            d[tid] = r0; d[tid + 256] = r1; d[tid + 512] = r2; d[tid + 768] = r3;
            if (q + 2 < NP) {
                pl = (const float4*)(x + ((size_t)(p0 + q + 2) << 12));
                r0 = pl[tid]; r1 = pl[tid + 256]; r2 = pl[tid + 512]; r3 = pl[tid + 768];
            }
            __syncthreads();   // buf^1 visible for compute(q+1)
        }
    }
}

extern "C" void kernel_launch(void* const* d_in, const int* in_sizes, int n_in,
                              void* d_out, int out_size, void* d_ws, size_t ws_size,
                              hipStream_t stream) {
    const float* x  = (const float*)d_in[0];
    const float* lm = (const float*)d_in[1];
    float* out = (float*)d_out;

    int blocks = BB * CC / NP;   // 1024
    roipool_kernel<<<blocks, 256, 0, stream>>>(x, lm, out);
}

// Round 15
// 29.830 us; speedup vs baseline: 1.5441x; 1.5441x over previous
//
#include <hip/hip_runtime.h>
#include <float.h>

#define BB 32
#define CC 128

// Streaming v3: block = ONE (b,c) plane; the whole 64MB input is read once,
// sequentially (4 float4 loads/thread = 16KB/block), at high occupancy so the
// aggregate stream saturates HBM (~6 TB/s) instead of scattered-window reads
// at ~1.25 TB/s. LDS 24.3KB -> 6 blocks/CU = 24 waves/CU (75%).
// Wave w computes landmarks {2w, 2w+1} from LDS; one barrier per block.
// Grid = 32*128 = 4096 blocks.
__global__ __launch_bounds__(256) void roipool_kernel(
    const float* __restrict__ x,   // [B,C,64,64]
    const float* __restrict__ lm,  // [B,16]
    float* __restrict__ out)       // [B,C,32,16]
{
    int plane = blockIdx.x;        // b*128 + c
    int b = plane >> 7;

    int tid  = threadIdx.x;
    int wave = tid >> 6;
    int lane = tid & 63;

    __shared__ float s[64][64];      // 16 KB: the full plane
    __shared__ float tb[4][8][65];   // 8.3 KB: per-wave bin-max (padded)

    // ---- sequential plane load: 4 x float4 per thread, one vmcnt group ----
    const float4* __restrict__ pl = (const float4*)(x + ((size_t)plane << 12));
    float4 r0 = pl[tid];
    float4 r1 = pl[tid + 256];
    float4 r2 = pl[tid + 512];
    float4 r3 = pl[tid + 768];
    {
        float4* d = (float4*)&s[0][0];
        d[tid]       = r0;
        d[tid + 256] = r1;
        d[tid + 512] = r2;
        d[tid + 768] = r3;
    }
    __syncthreads();

    int i = lane >> 3;   // cell row
    int j = lane & 7;    // cell col

    #pragma unroll
    for (int k = 0; k < 2; ++k) {
        int lmi = 2 * wave + k;      // wave-uniform landmark
        float x0 = lm[b * 16 + 2 * lmi];
        float y0 = lm[b * 16 + 2 * lmi + 1];
        bool visible = (x0 > 0.0f) || (y0 > 0.0f);

        // torchvision column-swap semantics:
        // rois=(b,x1,x2,y1,y2) consumed as (b,start_w,start_h,end_w,end_h)
        int fx = (int)floorf(x0 * 0.25f);
        int fy = (int)floorf(y0 * 0.25f);
        int roi = max(fy - fx + 1, 1);      // roi_w == roi_h; bin = roi/8 exact

        int orow = 8 * (lmi >> 1) + i;
        int ocol = 8 * (lmi & 1) + j;
        size_t oidx = ((size_t)plane * 32 + orow) * 16 + ocol;

        if (!visible) { out[oidx] = 0.0f; continue; }   // wave-uniform

        if (roi == 1) {   // all 64 cells = pixel (fx, fx-7); LDS broadcast
            int hs = min(max(fx, 0), 64),     he = min(max(fx + 1, 0), 64);
            int ws = min(max(fx - 7, 0), 64), we = min(max(fx - 6, 0), 64);
            bool empty = (he <= hs) || (we <= ws);
            out[oidx] = empty ? 0.0f : s[hs][ws];
            continue;
        }

        // ---- stage 1: per-column max per row-bin (lane = col); int bounds ----
        // floor(t*roi/8) = (t*roi)>>3, ceil = (+7)>>3 (exact: bin=roi/8 in fp32)
        #pragma unroll
        for (int t = 0; t < 8; ++t) {
            int hs = min(max(((t * roi) >> 3) + fx, 0), 64);
            int he = min(max((((t + 1) * roi + 7) >> 3) + fx, 0), 64);
            float acc = -FLT_MAX;
            for (int h = hs; h < he; h += 4) {
                int hm = he - 1;     // clamped dup rows harmless under max
                float a0 = s[h][lane];
                float a1 = s[min(h + 1, hm)][lane];
                float a2 = s[min(h + 2, hm)][lane];
                float a3 = s[min(h + 3, hm)][lane];
                acc = fmaxf(acc, fmaxf(fmaxf(a0, a1), fmaxf(a2, a3)));
            }
            tb[wave][t][lane] = acc;
        }

        // ---- stage 2: pool bin-max cols (same wave wrote tb -> no barrier);
        //      4-batched independent reads (no serial dependent LDS chain) ----
        int hs = min(max(((i * roi) >> 3) + fx, 0), 64);
        int he = min(max((((i + 1) * roi + 7) >> 3) + fx, 0), 64);
        int ws = min(max(((j * roi) >> 3) + fx - 7, 0), 64);
        int we = min(max((((j + 1) * roi + 7) >> 3) + fx - 7, 0), 64);
        bool empty = (he <= hs) || (we <= ws);

        float m = -FLT_MAX;
        if (!empty) {
            for (int w = ws; w < we; w += 4) {
                int wm = we - 1;     // clamped dup cols harmless under max
                float b0 = tb[wave][i][w];
                float b1 = tb[wave][i][min(w + 1, wm)];
                float b2 = tb[wave][i][min(w + 2, wm)];
                float b3 = tb[wave][i][min(w + 3, wm)];
                m = fmaxf(m, fmaxf(fmaxf(b0, b1), fmaxf(b2, b3)));
            }
        }
        out[oidx] = empty ? 0.0f : m;
    }
}

extern "C" void kernel_launch(void* const* d_in, const int* in_sizes, int n_in,
                              void* d_out, int out_size, void* d_ws, size_t ws_size,
                              hipStream_t stream) {
    const float* x  = (const float*)d_in[0];
    const float* lm = (const float*)d_in[1];
    float* out = (float*)d_out;

    int blocks = BB * CC;   // 4096
    roipool_kernel<<<blocks, 256, 0, stream>>>(x, lm, out);
}

// Round 16
// 21.371 us; speedup vs baseline: 2.1554x; 1.3959x over previous
//
#include <hip/hip_runtime.h>
#include <float.h>

#define BB 32
#define CC 128
#define HH 64
#define WW 64

// R13 structure (best: 22.2us) + two stall-structure fixes:
//  - stage 1: BOTH bins' load groups issued together (8 float4 in flight,
//    one exposed stall instead of two)
//  - stage 2: 4-batched independent LDS reads (kills the 9-deep serial
//    dependent ds_read chain)
// Block = 256 thr = 4 waves; wave w: bins {2w,2w+1} x 4 channels (stage 1),
// then channel w x 64 cells (stage 2). Grid = 32 b (fastest) * 8 * 32 = 8192.
__global__ __launch_bounds__(256) void roipool_kernel(
    const float* __restrict__ x,   // [B,C,64,64]
    const float* __restrict__ lm,  // [B,16]
    float* __restrict__ out)       // [B,C,32,16]
{
    int blk = blockIdx.x;
    int b   = blk & 31;
    int lmi = (blk >> 5) & 7;
    int cg  = blk >> 8;          // 0..31

    int tid  = threadIdx.x;
    int wave = tid >> 6;
    int lane = tid & 63;

    __shared__ float s[4][8][68];   // [ch][bin][col]; 68: pad, rows 16B-aligned

    float x0 = lm[b * 16 + 2 * lmi];
    float y0 = lm[b * 16 + 2 * lmi + 1];
    bool visible = (x0 > 0.0f) || (y0 > 0.0f);

    // torchvision column-swap semantics:
    // rois=(b,x1,x2,y1,y2) consumed as (b,start_w,start_h,end_w,end_h)
    int fx = (int)floorf(x0 * 0.25f);
    int fy = (int)floorf(y0 * 0.25f);
    int roi = max(fy - fx + 1, 1);      // roi_w == roi_h; bin = roi/8 exact

    int cbase = cg * 4;
    int i = lane >> 3;   // cell row
    int j = lane & 7;    // cell col
    int orow = 8 * (lmi >> 1) + i;
    int ocol = 8 * (lmi & 1) + j;

    // ---------- fast path: roi==1 -> every cell is pixel (fx, fx-7) ----------
    if (roi == 1) {                     // block-uniform branch
        int hs = min(max(fx, 0), HH),     he = min(max(fx + 1, 0), HH);
        int ws = min(max(fx - 7, 0), WW), we = min(max(fx - 6, 0), WW);
        bool empty = (he <= hs) || (we <= ws) || !visible;
        size_t c = (size_t)(cbase + wave);
        float v = 0.0f;
        if (!empty) v = x[(((size_t)b * CC + c) << 12) + (hs << 6) + ws];
        out[(((size_t)b * CC + c) * 32 + orow) * 16 + ocol] = empty ? 0.0f : v;
        return;
    }

    // clipped column window and its quad range
    int w0 = max(fx - 7, 0);
    int w1 = min(fx - 7 + roi, WW);
    int q0 = w0 >> 2;
    int q1 = (w1 - 1) >> 2;             // inclusive; negative if w1 <= 0

    int ch2 = lane >> 4;                // channel 0..3 within group
    int cq  = lane & 15;                // column quad 0..15

    const float* __restrict__ xq =
        x + (((size_t)b * CC + cbase + ch2) << 12) + (cq << 2);

    // ---- stage 1: bins {2w, 2w+1}, both issued together; float4 columns ----
    // Integer bin bounds (exact): floor(t*roi/8)=(t*roi)>>3, ceil=(+7)>>3.
    if (visible && cq >= q0 && cq <= q1) {
        int t0  = 2 * wave;
        int hs0 = min(max(((t0 * roi) >> 3) + fx, 0), HH);
        int he0 = min(max((((t0 + 1) * roi + 7) >> 3) + fx, 0), HH);
        int hs1 = min(max((((t0 + 1) * roi) >> 3) + fx, 0), HH);
        int he1 = min(max((((t0 + 2) * roi + 7) >> 3) + fx, 0), HH);
        // clamp rows into [0,63]; empty bins load dummy rows whose garbage
        // lands in tb slots stage 2 never reads (its he<=hs check zeroes them)
        int hm0 = max(he0 - 1, 0);
        int hm1 = max(he1 - 1, 0);
        int g   = max((he0 - hs0 + 3) >> 2, (he1 - hs1 + 3) >> 2);   // >= 1

        float a0 = -FLT_MAX, a1 = -FLT_MAX, a2 = -FLT_MAX, a3 = -FLT_MAX;
        float b0 = -FLT_MAX, b1 = -FLT_MAX, b2 = -FLT_MAX, b3 = -FLT_MAX;
        int hA = hs0, hB = hs1;
        for (int gg = 0; gg < g; ++gg, hA += 4, hB += 4) {
            // 8 independent float4 loads in flight (clamped dups harmless)
            float4 u0 = *(const float4*)(xq + (min(hA + 0, hm0) << 6));
            float4 u1 = *(const float4*)(xq + (min(hA + 1, hm0) << 6));
            float4 u2 = *(const float4*)(xq + (min(hA + 2, hm0) << 6));
            float4 u3 = *(const float4*)(xq + (min(hA + 3, hm0) << 6));
            float4 v0 = *(const float4*)(xq + (min(hB + 0, hm1) << 6));
            float4 v1 = *(const float4*)(xq + (min(hB + 1, hm1) << 6));
            float4 v2 = *(const float4*)(xq + (min(hB + 2, hm1) << 6));
            float4 v3 = *(const float4*)(xq + (min(hB + 3, hm1) << 6));
            a0 = fmaxf(a0, fmaxf(fmaxf(u0.x, u1.x), fmaxf(u2.x, u3.x)));
            a1 = fmaxf(a1, fmaxf(fmaxf(u0.y, u1.y), fmaxf(u2.y, u3.y)));
            a2 = fmaxf(a2, fmaxf(fmaxf(u0.z, u1.z), fmaxf(u2.z, u3.z)));
            a3 = fmaxf(a3, fmaxf(fmaxf(u0.w, u1.w), fmaxf(u2.w, u3.w)));
            b0 = fmaxf(b0, fmaxf(fmaxf(v0.x, v1.x), fmaxf(v2.x, v3.x)));
            b1 = fmaxf(b1, fmaxf(fmaxf(v0.y, v1.y), fmaxf(v2.y, v3.y)));
            b2 = fmaxf(b2, fmaxf(fmaxf(v0.z, v1.z), fmaxf(v2.z, v3.z)));
            b3 = fmaxf(b3, fmaxf(fmaxf(v0.w, v1.w), fmaxf(v2.w, v3.w)));
        }
        *(float4*)&s[ch2][t0][cq << 2]     = make_float4(a0, a1, a2, a3);
        *(float4*)&s[ch2][t0 + 1][cq << 2] = make_float4(b0, b1, b2, b3);
    }
    __syncthreads();

    // ---- stage 2: wave pools channel=wave; thread = cell (i,j); 4-batched ----
    int hs = min(max(((i * roi) >> 3) + fx, 0), HH);
    int he = min(max((((i + 1) * roi + 7) >> 3) + fx, 0), HH);
    int ws = min(max(((j * roi) >> 3) + fx - 7, 0), WW);
    int we = min(max((((j + 1) * roi + 7) >> 3) + fx - 7, 0), WW);
    bool empty = (he <= hs) || (we <= ws) || !visible;

    float m = -FLT_MAX;
    if (!empty) {
        for (int w = ws; w < we; w += 4) {
            int wm = we - 1;            // clamped dup cols harmless under max
            float c0 = s[wave][i][w];
            float c1 = s[wave][i][min(w + 1, wm)];
            float c2 = s[wave][i][min(w + 2, wm)];
            float c3 = s[wave][i][min(w + 3, wm)];
            m = fmaxf(m, fmaxf(fmaxf(c0, c1), fmaxf(c2, c3)));
        }
    }
    out[(((size_t)b * CC + cbase + wave) * 32 + orow) * 16 + ocol] = empty ? 0.0f : m;
}

extern "C" void kernel_launch(void* const* d_in, const int* in_sizes, int n_in,
                              void* d_out, int out_size, void* d_ws, size_t ws_size,
                              hipStream_t stream) {
    const float* x  = (const float*)d_in[0];
    const float* lm = (const float*)d_in[1];
    float* out = (float*)d_out;

    int blocks = BB * 8 * 32;   // 8192
    roipool_kernel<<<blocks, 256, 0, stream>>>(x, lm, out);
}